// Round 2
// baseline (1717.621 us; speedup 1.0000x reference)
//
#include <hip/hip_runtime.h>
#include <hip/hip_bf16.h>

#define N_NODES 100000
#define N_EDGES 3200000
#define TOT_E   (N_EDGES + N_NODES)   // edges + self loops = 3,300,000
#define HEADS   4
#define DH      16
#define IN_F    300
#define HID     64
#define OUT2    32
#define SLOPE   0.2f
#define SCAN_BLOCK 1024               // elements per scan block
#define SCAN_NB ((N_NODES + SCAN_BLOCK - 1) / SCAN_BLOCK)   // 98
#define KT      150                   // K-tile for gemm1 (300 = 2*150)

// ---------------- GEMM1: h[N,64] = x[N,300] @ W1[300,64] (fp32) --------------
__global__ __launch_bounds__(256) void k_gemm1(const float* __restrict__ x,
                                               const float* __restrict__ W1,
                                               float* __restrict__ h) {
    __shared__ float wlds[KT * HID];     // 38400 B
    __shared__ float xlds[16][KT + 2];   // 9728 B
    int t = threadIdx.x;
    int row0 = blockIdx.x * 64;
    int rr = t >> 4, cq = t & 15, c0 = cq * 4;
    float a[4][4];
#pragma unroll
    for (int i = 0; i < 4; i++)
#pragma unroll
        for (int j = 0; j < 4; j++) a[i][j] = 0.f;

    for (int kt = 0; kt < IN_F; kt += KT) {
        __syncthreads();   // previous tile fully consumed
        for (int i = t; i < KT * HID; i += 256) wlds[i] = W1[kt * HID + i];
        for (int rs = 0; rs < 4; rs++) {
            __syncthreads();   // xlds free to overwrite (and wlds visible at rs=0)
            for (int i = t; i < 16 * KT; i += 256) {
                int r2 = i / KT, kk = i - r2 * KT;
                int gr = row0 + rs * 16 + r2;
                xlds[r2][kk] = (gr < N_NODES) ? x[(size_t)gr * IN_F + kt + kk] : 0.f;
            }
            __syncthreads();
#pragma unroll 2
            for (int k = 0; k < KT; k++) {
                float xv = xlds[rr][k];
                float4 wv = *(const float4*)(wlds + k * HID + c0);
                a[rs][0] += xv * wv.x;
                a[rs][1] += xv * wv.y;
                a[rs][2] += xv * wv.z;
                a[rs][3] += xv * wv.w;
            }
        }
    }
#pragma unroll
    for (int rs = 0; rs < 4; rs++) {
        int gr = row0 + rs * 16 + rr;
        if (gr < N_NODES)
            *(float4*)&h[(size_t)gr * HID + c0] =
                make_float4(a[rs][0], a[rs][1], a[rs][2], a[rs][3]);
    }
}

// ---------------- attention scores: a_s[n,h], a_d[n,h] -----------------------
__global__ void k_scores(const float* __restrict__ h,
                         const float* __restrict__ att_src,
                         const float* __restrict__ att_dst,
                         float* __restrict__ as_ad) {
    int tid = blockIdx.x * blockDim.x + threadIdx.x;
    if (tid >= N_NODES * HEADS) return;
    int n = tid >> 2, hd = tid & 3;
    const float* hp = &h[(size_t)n * HID + hd * DH];
    float s = 0.f, d = 0.f;
#pragma unroll
    for (int k = 0; k < DH; k++) {
        float v = hp[k];
        s += v * att_src[hd * DH + k];
        d += v * att_dst[hd * DH + k];
    }
    as_ad[n * 8 + hd] = s;
    as_ad[n * 8 + 4 + hd] = d;
}

// ---------------- histogram of dst (incl. self loops) ------------------------
__global__ void k_hist(const int* __restrict__ ei, int* __restrict__ counts) {
    int e = blockIdx.x * blockDim.x + threadIdx.x;
    if (e >= TOT_E) return;
    int dst = (e < N_EDGES) ? ei[N_EDGES + e] : (e - N_EDGES);
    atomicAdd(&counts[dst], 1);
}

// ---------------- 3-kernel exclusive scan (N=100000) -------------------------
__global__ void k_scan_sums(const int* __restrict__ counts, int* __restrict__ bsum) {
    __shared__ int sm[256];
    int b = blockIdx.x, t = threadIdx.x;
    int base = b * SCAN_BLOCK + t * 4;
    int s = 0;
#pragma unroll
    for (int i = 0; i < 4; i++) { int idx = base + i; if (idx < N_NODES) s += counts[idx]; }
    sm[t] = s; __syncthreads();
    for (int off = 128; off > 0; off >>= 1) {
        if (t < off) sm[t] += sm[t + off];
        __syncthreads();
    }
    if (t == 0) bsum[b] = sm[0];
}
__global__ void k_scan_top(int* __restrict__ bsum) {
    if (threadIdx.x == 0) {
        int ex = 0;
        for (int i = 0; i < SCAN_NB; i++) { int v = bsum[i]; bsum[i] = ex; ex += v; }
    }
}
__global__ void k_scan_final(const int* __restrict__ counts, const int* __restrict__ bsum,
                             int* __restrict__ rowptr) {
    __shared__ int sm[256];
    int b = blockIdx.x, t = threadIdx.x;
    int base = b * SCAN_BLOCK + t * 4;
    int v[4]; int s = 0;
#pragma unroll
    for (int i = 0; i < 4; i++) {
        v[i] = (base + i < N_NODES) ? counts[base + i] : 0;
        s += v[i];
    }
    sm[t] = s; __syncthreads();
    for (int off = 1; off < 256; off <<= 1) {
        int x = 0;
        if (t >= off) x = sm[t - off];
        __syncthreads();
        sm[t] += x;
        __syncthreads();
    }
    int excl = sm[t] - s;
    int run = bsum[b] + excl;
#pragma unroll
    for (int i = 0; i < 4; i++) {
        if (base + i < N_NODES) rowptr[base + i] = run;
        run += v[i];
    }
}

// ---------------- scatter edges into CSR slots -------------------------------
__global__ void k_scatter(const int* __restrict__ ei, int* __restrict__ cursor,
                          int* __restrict__ srcs) {
    int e = blockIdx.x * blockDim.x + threadIdx.x;
    if (e >= TOT_E) return;
    int src, dst;
    if (e < N_EDGES) { src = ei[e]; dst = ei[N_EDGES + e]; }
    else             { src = e - N_EDGES; dst = src; }
    int pos = atomicAdd(&cursor[dst], 1);
    srcs[pos] = src;
}

// ---------------- dinv = rsqrt(in-degree) ------------------------------------
__global__ void k_dinv(const int* __restrict__ counts2, float* __restrict__ dinv) {
    int n = blockIdx.x * blockDim.x + threadIdx.x;
    if (n >= N_NODES) return;
    int d = counts2[n];
    dinv[n] = (d > 0) ? rsqrtf((float)d) : 0.f;
}

// ---------------- GAT aggregation: wave per dst, online softmax --------------
__global__ __launch_bounds__(256) void k_gat(const float* __restrict__ h,
                                             const float* __restrict__ as_ad,
                                             const int* __restrict__ rowptr,
                                             const int* __restrict__ srcs,
                                             const float* __restrict__ b1,
                                             float* __restrict__ x1) {
    int w = (blockIdx.x * 256 + threadIdx.x) >> 6;   // wave-uniform dst node
    if (w >= N_NODES) return;
    int lane = threadIdx.x & 63;
    int hd = lane >> 4;
    float ad = as_ad[w * 8 + 4 + hd];
    float m = -1e30f, l = 0.f, acc = 0.f;
    int beg = rowptr[w];
    int end = (w == N_NODES - 1) ? TOT_E : rowptr[w + 1];
    for (int j = beg; j < end; j++) {
        int s = srcs[j];
        float e = as_ad[s * 8 + hd] + ad;
        e = (e > 0.f) ? e : SLOPE * e;
        float mn = fmaxf(m, e);
        float sc = __expf(m - mn);     // 0 on first iter (m=-1e30)
        float p  = __expf(e - mn);
        l = l * sc + p;
        acc = acc * sc + p * h[(size_t)s * HID + lane];
        m = mn;
    }
    x1[(size_t)w * HID + lane] = fmaxf(acc / l + b1[lane], 0.f);
}

// ---------------- GEMM2: h2[N,32] = x1[N,64] @ W2[64,32] ---------------------
__global__ __launch_bounds__(256) void k_gemm2(const float* __restrict__ x1,
                                               const float* __restrict__ W2,
                                               float* __restrict__ h2) {
    __shared__ float wl[HID * OUT2];   // 8 KB
    __shared__ float xl[8][HID];       // 2 KB
    int t = threadIdx.x;
    for (int i = t; i < HID * OUT2; i += 256) wl[i] = W2[i];
    int row0 = blockIdx.x * 8;
    for (int i = t; i < 8 * HID; i += 256) {
        int rr = i >> 6, kk = i & 63;
        int gr = row0 + rr;
        xl[rr][kk] = (gr < N_NODES) ? x1[(size_t)gr * HID + kk] : 0.f;
    }
    __syncthreads();
    int r = t >> 5, c = t & 31;
    float acc = 0.f;
#pragma unroll 8
    for (int k = 0; k < HID; k++) acc += xl[r][k] * wl[k * OUT2 + c];
    int gr = row0 + r;
    if (gr < N_NODES) h2[(size_t)gr * OUT2 + c] = acc;
}

// ---------------- GCN aggregation: wave per dst (2-edge ILP) -----------------
__global__ __launch_bounds__(256) void k_gcn(const float* __restrict__ h2,
                                             const float* __restrict__ dinv,
                                             const int* __restrict__ rowptr,
                                             const int* __restrict__ srcs,
                                             const float* __restrict__ b2,
                                             float* __restrict__ out) {
    int w = (blockIdx.x * 256 + threadIdx.x) >> 6;
    if (w >= N_NODES) return;
    int lane = threadIdx.x & 63;
    int c = lane & 31, rep = lane >> 5;
    int beg = rowptr[w];
    int end = (w == N_NODES - 1) ? TOT_E : rowptr[w + 1];
    float acc = 0.f;
    for (int j = beg + rep; j < end; j += 2) {
        int s = srcs[j];
        acc += h2[(size_t)s * OUT2 + c] * dinv[s];
    }
    acc += __shfl_xor(acc, 32, 64);
    if (rep == 0) out[(size_t)w * OUT2 + c] = acc * dinv[w] + b2[c];
}

// ---------------- launch -----------------------------------------------------
static inline size_t align_up(size_t v, size_t a) { return (v + a - 1) & ~(a - 1); }

extern "C" void kernel_launch(void* const* d_in, const int* in_sizes, int n_in,
                              void* d_out, int out_size, void* d_ws, size_t ws_size,
                              hipStream_t stream) {
    const float* x       = (const float*)d_in[0];
    const float* W1      = (const float*)d_in[1];
    const float* att_src = (const float*)d_in[2];
    const float* att_dst = (const float*)d_in[3];
    const float* b1      = (const float*)d_in[4];
    const float* W2      = (const float*)d_in[5];
    const float* b2      = (const float*)d_in[6];
    const int*   ei1     = (const int*)d_in[7];
    const int*   ei2     = (const int*)d_in[8];
    float* out = (float*)d_out;

    // workspace carve (~96.4 MB total)
    char* p = (char*)d_ws;
    size_t off = 0;
    auto carve = [&](size_t bytes) { void* q = p + off; off = align_up(off + bytes, 256); return q; };
    float* h      = (float*)carve((size_t)N_NODES * HID * 4);
    float* x1     = (float*)carve((size_t)N_NODES * HID * 4);
    float* h2     = (float*)carve((size_t)N_NODES * OUT2 * 4);
    float* as_ad  = (float*)carve((size_t)N_NODES * 8 * 4);
    float* dinv   = (float*)carve((size_t)N_NODES * 4);
    int* counts1  = (int*)carve((size_t)N_NODES * 4);
    int* rowptr1  = (int*)carve((size_t)N_NODES * 4);
    int* cursor1  = (int*)carve((size_t)N_NODES * 4);
    int* srcs1    = (int*)carve((size_t)TOT_E * 4);
    int* counts2  = (int*)carve((size_t)N_NODES * 4);
    int* rowptr2  = (int*)carve((size_t)N_NODES * 4);
    int* cursor2  = (int*)carve((size_t)N_NODES * 4);
    int* srcs2    = (int*)carve((size_t)TOT_E * 4);
    int* bsum     = (int*)carve((size_t)SCAN_NB * 4);
    (void)ws_size; (void)in_sizes; (void)n_in; (void)out_size;

    hipMemsetAsync(counts1, 0, (size_t)N_NODES * 4, stream);
    hipMemsetAsync(counts2, 0, (size_t)N_NODES * 4, stream);

    // GEMM1 + scores
    k_gemm1<<<(N_NODES + 63) / 64, 256, 0, stream>>>(x, W1, h);
    k_scores<<<(N_NODES * HEADS + 255) / 256, 256, 0, stream>>>(h, att_src, att_dst, as_ad);

    // histograms
    int eb = (TOT_E + 255) / 256;
    k_hist<<<eb, 256, 0, stream>>>(ei1, counts1);
    k_hist<<<eb, 256, 0, stream>>>(ei2, counts2);

    // CSR 1 (GAT edges)
    k_scan_sums<<<SCAN_NB, 256, 0, stream>>>(counts1, bsum);
    k_scan_top<<<1, 64, 0, stream>>>(bsum);
    k_scan_final<<<SCAN_NB, 256, 0, stream>>>(counts1, bsum, rowptr1);
    hipMemcpyAsync(cursor1, rowptr1, (size_t)N_NODES * 4, hipMemcpyDeviceToDevice, stream);
    k_scatter<<<eb, 256, 0, stream>>>(ei1, cursor1, srcs1);

    // CSR 2 (GCN edges)
    k_scan_sums<<<SCAN_NB, 256, 0, stream>>>(counts2, bsum);
    k_scan_top<<<1, 64, 0, stream>>>(bsum);
    k_scan_final<<<SCAN_NB, 256, 0, stream>>>(counts2, bsum, rowptr2);
    hipMemcpyAsync(cursor2, rowptr2, (size_t)N_NODES * 4, hipMemcpyDeviceToDevice, stream);
    k_scatter<<<eb, 256, 0, stream>>>(ei2, cursor2, srcs2);

    k_dinv<<<(N_NODES + 255) / 256, 256, 0, stream>>>(counts2, dinv);

    // GAT aggregation -> x1 (relu(+b1) fused)
    k_gat<<<N_NODES / 4, 256, 0, stream>>>(h, as_ad, rowptr1, srcs1, b1, x1);

    // GEMM2 -> h2
    k_gemm2<<<N_NODES / 8, 256, 0, stream>>>(x1, W2, h2);

    // GCN aggregation -> out (+b2 fused)
    k_gcn<<<N_NODES / 4, 256, 0, stream>>>(h2, dinv, rowptr2, srcs2, b2, out);
}

// Round 3
// 1452.274 us; speedup vs baseline: 1.1827x; 1.1827x over previous
//
#include <hip/hip_runtime.h>
#include <hip/hip_bf16.h>

#define N_NODES 100000
#define N_EDGES 3200000
#define TOT_E   (N_EDGES + N_NODES)   // edges + self loops = 3,300,000
#define HEADS   4
#define DH      16
#define IN_F    300
#define HID     64
#define OUT2    32
#define SLOPE   0.2f
#define SCAN_BLOCK 1024               // elements per scan block
#define SCAN_NB ((N_NODES + SCAN_BLOCK - 1) / SCAN_BLOCK)   // 98
#define KT      150                   // K-tile for gemm1 (300 = 2*150)
#define EB      ((TOT_E + 255) / 256) // edge blocks

// ---------------- GEMM1: h[N,64] = x[N,300] @ W1[300,64] (fp32) --------------
__global__ __launch_bounds__(256) void k_gemm1(const float* __restrict__ x,
                                               const float* __restrict__ W1,
                                               float* __restrict__ h) {
    __shared__ float wlds[KT * HID];     // 38400 B
    __shared__ float xlds[16][KT + 2];   // 9728 B
    int t = threadIdx.x;
    int row0 = blockIdx.x * 64;
    int rr = t >> 4, cq = t & 15, c0 = cq * 4;
    float a[4][4];
#pragma unroll
    for (int i = 0; i < 4; i++)
#pragma unroll
        for (int j = 0; j < 4; j++) a[i][j] = 0.f;

    for (int kt = 0; kt < IN_F; kt += KT) {
        __syncthreads();
        for (int i = t; i < KT * HID; i += 256) wlds[i] = W1[kt * HID + i];
        for (int rs = 0; rs < 4; rs++) {
            __syncthreads();
            for (int i = t; i < 16 * KT; i += 256) {
                int r2 = i / KT, kk = i - r2 * KT;
                int gr = row0 + rs * 16 + r2;
                xlds[r2][kk] = (gr < N_NODES) ? x[(size_t)gr * IN_F + kt + kk] : 0.f;
            }
            __syncthreads();
#pragma unroll 2
            for (int k = 0; k < KT; k++) {
                float xv = xlds[rr][k];
                float4 wv = *(const float4*)(wlds + k * HID + c0);
                a[rs][0] += xv * wv.x;
                a[rs][1] += xv * wv.y;
                a[rs][2] += xv * wv.z;
                a[rs][3] += xv * wv.w;
            }
        }
    }
#pragma unroll
    for (int rs = 0; rs < 4; rs++) {
        int gr = row0 + rs * 16 + rr;
        if (gr < N_NODES)
            *(float4*)&h[(size_t)gr * HID + c0] =
                make_float4(a[rs][0], a[rs][1], a[rs][2], a[rs][3]);
    }
}

// ---------------- attention scores: a_s[n,h], a_d[n,h] -----------------------
__global__ void k_scores(const float* __restrict__ h,
                         const float* __restrict__ att_src,
                         const float* __restrict__ att_dst,
                         float* __restrict__ as_ad) {
    int tid = blockIdx.x * blockDim.x + threadIdx.x;
    if (tid >= N_NODES * HEADS) return;
    int n = tid >> 2, hd = tid & 3;
    const float* hp = &h[(size_t)n * HID + hd * DH];
    float s = 0.f, d = 0.f;
#pragma unroll
    for (int k = 0; k < DH; k++) {
        float v = hp[k];
        s += v * att_src[hd * DH + k];
        d += v * att_dst[hd * DH + k];
    }
    as_ad[n * 8 + hd] = s;
    as_ad[n * 8 + 4 + hd] = d;
}

// ---------------- fused histogram: both edge lists ---------------------------
__global__ void k_hist2(const int* __restrict__ ei1, const int* __restrict__ ei2,
                        int* __restrict__ counts) {
    int b = blockIdx.x;
    const int* ei; int* cnt;
    if (b < EB) { ei = ei1; cnt = counts; }
    else        { ei = ei2; cnt = counts + N_NODES; b -= EB; }
    int e = b * 256 + threadIdx.x;
    if (e >= TOT_E) return;
    int dst = (e < N_EDGES) ? ei[N_EDGES + e] : (e - N_EDGES);
    atomicAdd(&cnt[dst], 1);
}

// ---------------- fused 2-list exclusive scan --------------------------------
__global__ void k_scan_sums(const int* __restrict__ counts, int* __restrict__ bsum) {
    __shared__ int sm[256];
    int list = blockIdx.x / SCAN_NB, b = blockIdx.x % SCAN_NB, t = threadIdx.x;
    const int* cnt = counts + list * N_NODES;
    int base = b * SCAN_BLOCK + t * 4;
    int s = 0;
#pragma unroll
    for (int i = 0; i < 4; i++) { int idx = base + i; if (idx < N_NODES) s += cnt[idx]; }
    sm[t] = s; __syncthreads();
    for (int off = 128; off > 0; off >>= 1) {
        if (t < off) sm[t] += sm[t + off];
        __syncthreads();
    }
    if (t == 0) bsum[blockIdx.x] = sm[0];
}
__global__ void k_scan_top(int* __restrict__ bsum) {
    int t = threadIdx.x;
    if (t == 0 || t == 64) {
        int* bp = bsum + (t ? SCAN_NB : 0);
        int ex = 0;
        for (int i = 0; i < SCAN_NB; i++) { int v = bp[i]; bp[i] = ex; ex += v; }
    }
}
// writes rowptr AND cursor; list 1 also writes dinv = rsqrt(count)
__global__ void k_scan_final(const int* __restrict__ counts, const int* __restrict__ bsum,
                             int* __restrict__ rowptr, int* __restrict__ cursor,
                             float* __restrict__ dinv) {
    __shared__ int sm[256];
    int list = blockIdx.x / SCAN_NB, b = blockIdx.x % SCAN_NB, t = threadIdx.x;
    const int* cnt = counts + list * N_NODES;
    int* rp = rowptr + list * N_NODES;
    int* cu = cursor + list * N_NODES;
    int base = b * SCAN_BLOCK + t * 4;
    int v[4]; int s = 0;
#pragma unroll
    for (int i = 0; i < 4; i++) {
        v[i] = (base + i < N_NODES) ? cnt[base + i] : 0;
        s += v[i];
    }
    sm[t] = s; __syncthreads();
    for (int off = 1; off < 256; off <<= 1) {
        int x = 0;
        if (t >= off) x = sm[t - off];
        __syncthreads();
        sm[t] += x;
        __syncthreads();
    }
    int run = bsum[blockIdx.x] + sm[t] - s;
#pragma unroll
    for (int i = 0; i < 4; i++) {
        int idx = base + i;
        if (idx < N_NODES) {
            rp[idx] = run; cu[idx] = run;
            if (list == 1) dinv[idx] = (v[i] > 0) ? rsqrtf((float)v[i]) : 0.f;
        }
        run += v[i];
    }
}

// ---------------- fused scatter: both edge lists -----------------------------
__global__ void k_scatter2(const int* __restrict__ ei1, const int* __restrict__ ei2,
                           int* __restrict__ cursor, int* __restrict__ srcs) {
    int b = blockIdx.x;
    const int* ei; int* cu; int* sc;
    if (b < EB) { ei = ei1; cu = cursor; sc = srcs; }
    else        { ei = ei2; cu = cursor + N_NODES; sc = srcs + TOT_E; b -= EB; }
    int e = b * 256 + threadIdx.x;
    if (e >= TOT_E) return;
    int src, dst;
    if (e < N_EDGES) { src = ei[e]; dst = ei[N_EDGES + e]; }
    else             { src = e - N_EDGES; dst = src; }
    int pos = atomicAdd(&cu[dst], 1);
    sc[pos] = src;
}

// ---------------- GAT aggregation: wave/dst, direct exp, 4-edge ILP ----------
__global__ __launch_bounds__(256) void k_gat(const float* __restrict__ h,
                                             const float* __restrict__ as_ad,
                                             const int* __restrict__ rowptr,
                                             const int* __restrict__ srcs,
                                             const float* __restrict__ b1,
                                             float* __restrict__ x1) {
    int w = (blockIdx.x * 256 + threadIdx.x) >> 6;   // wave-uniform dst node
    if (w >= N_NODES) return;
    int lane = threadIdx.x & 63;
    int hd = lane >> 4;
    float ad = as_ad[w * 8 + 4 + hd];
    int beg = rowptr[w];
    int end = (w == N_NODES - 1) ? TOT_E : rowptr[w + 1];
    float l0 = 0.f, l1 = 0.f, a0 = 0.f, a1 = 0.f;
    int j = beg;
    for (; j + 3 < end; j += 4) {
        int s0 = srcs[j], s1 = srcs[j + 1], s2 = srcs[j + 2], s3 = srcs[j + 3];
        float h0 = h[(size_t)s0 * HID + lane];
        float h1 = h[(size_t)s1 * HID + lane];
        float h2 = h[(size_t)s2 * HID + lane];
        float h3 = h[(size_t)s3 * HID + lane];
        float e0 = as_ad[s0 * 8 + hd] + ad;
        float e1 = as_ad[s1 * 8 + hd] + ad;
        float e2 = as_ad[s2 * 8 + hd] + ad;
        float e3 = as_ad[s3 * 8 + hd] + ad;
        e0 = fminf((e0 > 0.f) ? e0 : SLOPE * e0, 60.f);
        e1 = fminf((e1 > 0.f) ? e1 : SLOPE * e1, 60.f);
        e2 = fminf((e2 > 0.f) ? e2 : SLOPE * e2, 60.f);
        e3 = fminf((e3 > 0.f) ? e3 : SLOPE * e3, 60.f);
        float p0 = __expf(e0), p1 = __expf(e1), p2 = __expf(e2), p3 = __expf(e3);
        l0 += p0; l1 += p1; l0 += p2; l1 += p3;
        a0 += p0 * h0; a1 += p1 * h1; a0 += p2 * h2; a1 += p3 * h3;
    }
    for (; j < end; j++) {
        int s = srcs[j];
        float hv = h[(size_t)s * HID + lane];
        float e = as_ad[s * 8 + hd] + ad;
        e = fminf((e > 0.f) ? e : SLOPE * e, 60.f);
        float p = __expf(e);
        l0 += p; a0 += p * hv;
    }
    float l = l0 + l1, acc = a0 + a1;
    x1[(size_t)w * HID + lane] = fmaxf(acc / l + b1[lane], 0.f);
}

// ---------------- GEMM2: h2s[N,32] = (x1[N,64] @ W2[64,32]) * dinv[row] ------
__global__ __launch_bounds__(256) void k_gemm2(const float* __restrict__ x1,
                                               const float* __restrict__ W2,
                                               const float* __restrict__ dinv,
                                               float* __restrict__ h2s) {
    __shared__ float wl[HID * OUT2];   // 8 KB
    __shared__ float xl[8][HID];       // 2 KB
    int t = threadIdx.x;
    for (int i = t; i < HID * OUT2; i += 256) wl[i] = W2[i];
    int row0 = blockIdx.x * 8;
    for (int i = t; i < 8 * HID; i += 256) {
        int rr = i >> 6, kk = i & 63;
        int gr = row0 + rr;
        xl[rr][kk] = (gr < N_NODES) ? x1[(size_t)gr * HID + kk] : 0.f;
    }
    __syncthreads();
    int r = t >> 5, c = t & 31;
    float acc = 0.f;
#pragma unroll 8
    for (int k = 0; k < HID; k++) acc += xl[r][k] * wl[k * OUT2 + c];
    int gr = row0 + r;
    if (gr < N_NODES) h2s[(size_t)gr * OUT2 + c] = acc * dinv[gr];
}

// ---------------- GCN aggregation: wave/dst, 4-edge ILP ----------------------
__global__ __launch_bounds__(256) void k_gcn(const float* __restrict__ h2s,
                                             const float* __restrict__ dinv,
                                             const int* __restrict__ rowptr,
                                             const int* __restrict__ srcs,
                                             const float* __restrict__ b2,
                                             float* __restrict__ out) {
    int w = (blockIdx.x * 256 + threadIdx.x) >> 6;
    if (w >= N_NODES) return;
    int lane = threadIdx.x & 63;
    int c = lane & 31, rep = lane >> 5;
    int beg = rowptr[w];
    int end = (w == N_NODES - 1) ? TOT_E : rowptr[w + 1];
    float a0 = 0.f, a1 = 0.f;
    int j = beg + rep;
    for (; j + 2 < end; j += 4) {       // this rep handles j, j+2 (other rep j+1, j+3)
        int s0 = srcs[j], s1 = srcs[j + 2];
        a0 += h2s[(size_t)s0 * OUT2 + c];
        a1 += h2s[(size_t)s1 * OUT2 + c];
    }
    if (j < end) a0 += h2s[(size_t)srcs[j] * OUT2 + c];
    float acc = a0 + a1;
    acc += __shfl_xor(acc, 32, 64);
    if (rep == 0) out[(size_t)w * OUT2 + c] = acc * dinv[w] + b2[c];
}

// ---------------- launch -----------------------------------------------------
static inline size_t align_up(size_t v, size_t a) { return (v + a - 1) & ~(a - 1); }

extern "C" void kernel_launch(void* const* d_in, const int* in_sizes, int n_in,
                              void* d_out, int out_size, void* d_ws, size_t ws_size,
                              hipStream_t stream) {
    const float* x       = (const float*)d_in[0];
    const float* W1      = (const float*)d_in[1];
    const float* att_src = (const float*)d_in[2];
    const float* att_dst = (const float*)d_in[3];
    const float* b1      = (const float*)d_in[4];
    const float* W2      = (const float*)d_in[5];
    const float* b2      = (const float*)d_in[6];
    const int*   ei1     = (const int*)d_in[7];
    const int*   ei2     = (const int*)d_in[8];
    float* out = (float*)d_out;

    char* p = (char*)d_ws;
    size_t off = 0;
    auto carve = [&](size_t bytes) { void* q = p + off; off = align_up(off + bytes, 256); return q; };
    float* h      = (float*)carve((size_t)N_NODES * HID * 4);
    float* x1     = (float*)carve((size_t)N_NODES * HID * 4);
    float* h2s    = (float*)carve((size_t)N_NODES * OUT2 * 4);
    float* as_ad  = (float*)carve((size_t)N_NODES * 8 * 4);
    float* dinv   = (float*)carve((size_t)N_NODES * 4);
    int* counts   = (int*)carve((size_t)2 * N_NODES * 4);   // [list0 | list1]
    int* rowptr   = (int*)carve((size_t)2 * N_NODES * 4);
    int* cursor   = (int*)carve((size_t)2 * N_NODES * 4);
    int* srcs     = (int*)carve((size_t)2 * TOT_E * 4);     // [list0 | list1]
    int* bsum     = (int*)carve((size_t)2 * SCAN_NB * 4);
    (void)ws_size; (void)in_sizes; (void)n_in; (void)out_size;

    hipMemsetAsync(counts, 0, (size_t)2 * N_NODES * 4, stream);

    // GEMM1 + scores
    k_gemm1<<<(N_NODES + 63) / 64, 256, 0, stream>>>(x, W1, h);
    k_scores<<<(N_NODES * HEADS + 255) / 256, 256, 0, stream>>>(h, att_src, att_dst, as_ad);

    // CSR build (both lists fused)
    k_hist2<<<2 * EB, 256, 0, stream>>>(ei1, ei2, counts);
    k_scan_sums<<<2 * SCAN_NB, 256, 0, stream>>>(counts, bsum);
    k_scan_top<<<1, 128, 0, stream>>>(bsum);
    k_scan_final<<<2 * SCAN_NB, 256, 0, stream>>>(counts, bsum, rowptr, cursor, dinv);
    k_scatter2<<<2 * EB, 256, 0, stream>>>(ei1, ei2, cursor, srcs);

    // GAT aggregation -> x1 (relu(+b1) fused)
    k_gat<<<N_NODES / 4, 256, 0, stream>>>(h, as_ad, rowptr, srcs, b1, x1);

    // GEMM2 -> h2s (pre-scaled by dinv[row])
    k_gemm2<<<N_NODES / 8, 256, 0, stream>>>(x1, W2, dinv, h2s);

    // GCN aggregation -> out (+b2 fused)
    k_gcn<<<N_NODES / 4, 256, 0, stream>>>(h2s, dinv, rowptr + N_NODES, srcs + TOT_E, b2, out);
}

// Round 4
// 836.936 us; speedup vs baseline: 2.0523x; 1.7352x over previous
//
#include <hip/hip_runtime.h>
#include <hip/hip_bf16.h>

#define N_NODES 100000
#define N_EDGES 3200000
#define TOT_E   (N_EDGES + N_NODES)   // edges + self loops = 3,300,000
#define HEADS   4
#define DH      16
#define IN_F    300
#define HID     64
#define OUT2    32
#define SLOPE   0.2f
#define KT      150                   // K-tile for gemm1 (300 = 2*150)
#define NBK     256                   // coarse buckets per list
#define GSZ     391                   // nodes per coarse bucket (256*391 >= 100000)
#define EBLK    4096                  // edges per bin block
#define NBA     ((TOT_E + EBLK - 1) / EBLK)   // 806 blocks per list

// ---------------- GEMM1: h[N,64] = x[N,300] @ W1[300,64] (fp32) --------------
__global__ __launch_bounds__(256) void k_gemm1(const float* __restrict__ x,
                                               const float* __restrict__ W1,
                                               float* __restrict__ h) {
    __shared__ float wlds[KT * HID];     // 38400 B
    __shared__ float xlds[16][KT + 2];   // 9728 B
    int t = threadIdx.x;
    int row0 = blockIdx.x * 64;
    int rr = t >> 4, cq = t & 15, c0 = cq * 4;
    float a[4][4];
#pragma unroll
    for (int i = 0; i < 4; i++)
#pragma unroll
        for (int j = 0; j < 4; j++) a[i][j] = 0.f;

    for (int kt = 0; kt < IN_F; kt += KT) {
        __syncthreads();
        for (int i = t; i < KT * HID; i += 256) wlds[i] = W1[kt * HID + i];
        for (int rs = 0; rs < 4; rs++) {
            __syncthreads();
            for (int i = t; i < 16 * KT; i += 256) {
                int r2 = i / KT, kk = i - r2 * KT;
                int gr = row0 + rs * 16 + r2;
                xlds[r2][kk] = (gr < N_NODES) ? x[(size_t)gr * IN_F + kt + kk] : 0.f;
            }
            __syncthreads();
#pragma unroll 2
            for (int k = 0; k < KT; k++) {
                float xv = xlds[rr][k];
                float4 wv = *(const float4*)(wlds + k * HID + c0);
                a[rs][0] += xv * wv.x;
                a[rs][1] += xv * wv.y;
                a[rs][2] += xv * wv.z;
                a[rs][3] += xv * wv.w;
            }
        }
    }
#pragma unroll
    for (int rs = 0; rs < 4; rs++) {
        int gr = row0 + rs * 16 + rr;
        if (gr < N_NODES)
            *(float4*)&h[(size_t)gr * HID + c0] =
                make_float4(a[rs][0], a[rs][1], a[rs][2], a[rs][3]);
    }
}

// ---------------- attention scores: a_s[n,h], a_d[n,h] -----------------------
__global__ void k_scores(const float* __restrict__ h,
                         const float* __restrict__ att_src,
                         const float* __restrict__ att_dst,
                         float* __restrict__ as_ad) {
    int tid = blockIdx.x * blockDim.x + threadIdx.x;
    if (tid >= N_NODES * HEADS) return;
    int n = tid >> 2, hd = tid & 3;
    const float* hp = &h[(size_t)n * HID + hd * DH];
    float s = 0.f, d = 0.f;
#pragma unroll
    for (int k = 0; k < DH; k++) {
        float v = hp[k];
        s += v * att_src[hd * DH + k];
        d += v * att_dst[hd * DH + k];
    }
    as_ad[n * 8 + hd] = s;
    as_ad[n * 8 + 4 + hd] = d;
}

// ---------------- coarse histogram (LDS-aggregated, both lists) --------------
__global__ __launch_bounds__(512) void k_chist(const int* __restrict__ ei1,
                                               const int* __restrict__ ei2,
                                               int* __restrict__ ccnt) {
    __shared__ int hist[NBK];
    int b = blockIdx.x; const int* ei; int* cc;
    if (b < NBA) { ei = ei1; cc = ccnt; }
    else         { ei = ei2; cc = ccnt + NBK; b -= NBA; }
    int t = threadIdx.x;
    if (t < NBK) hist[t] = 0;
    __syncthreads();
    int e0 = b * EBLK;
#pragma unroll
    for (int i = 0; i < 8; i++) {
        int e = e0 + i * 512 + t;
        if (e < TOT_E) {
            int dst = (e < N_EDGES) ? ei[N_EDGES + e] : (e - N_EDGES);
            atomicAdd(&hist[(unsigned int)dst / GSZ], 1);
        }
    }
    __syncthreads();
    if (t < NBK) { int v = hist[t]; if (v) atomicAdd(&cc[t], v); }
}

// ---------------- coarse scan (1 block, 2 lists x 256) -----------------------
__global__ __launch_bounds__(512) void k_cscan(const int* __restrict__ ccnt,
                                               int* __restrict__ crp,
                                               int* __restrict__ ccur) {
    __shared__ int sc[512];
    int t = threadIdx.x;
    int idx = t & (NBK - 1);
    int own = ccnt[t];
    sc[t] = own;
    __syncthreads();
    for (int off = 1; off < NBK; off <<= 1) {
        int v = (idx >= off) ? sc[t - off] : 0;
        __syncthreads();
        sc[t] += v;
        __syncthreads();
    }
    int ex = sc[t] - own;
    crp[t] = ex; ccur[t] = ex;
}

// ---------------- coarse bin: scatter packed (dst_lo<<17 | src) --------------
__global__ __launch_bounds__(512) void k_binA(const int* __restrict__ ei1,
                                              const int* __restrict__ ei2,
                                              int* __restrict__ ccur,
                                              unsigned int* __restrict__ tmp) {
    __shared__ int hist[NBK];
    __shared__ int base[NBK];
    int b = blockIdx.x; const int* ei; int loff;
    if (b < NBA) { ei = ei1; loff = 0; }
    else         { ei = ei2; loff = 1; b -= NBA; }
    int t = threadIdx.x;
    if (t < NBK) hist[t] = 0;
    __syncthreads();
    unsigned int pk[8]; int cb[8], rk[8];
    int e0 = b * EBLK;
#pragma unroll
    for (int i = 0; i < 8; i++) {
        int e = e0 + i * 512 + t;
        cb[i] = -1;
        if (e < TOT_E) {
            int src, dst;
            if (e < N_EDGES) { src = ei[e]; dst = ei[N_EDGES + e]; }
            else             { src = e - N_EDGES; dst = src; }
            unsigned int c   = (unsigned int)dst / GSZ;
            unsigned int dlo = (unsigned int)dst - c * GSZ;
            cb[i] = (int)c;
            pk[i] = (dlo << 17) | (unsigned int)src;
            rk[i] = atomicAdd(&hist[c], 1);
        }
    }
    __syncthreads();
    if (t < NBK) {
        int v = hist[t];
        base[t] = v ? atomicAdd(&ccur[loff * NBK + t], v) : 0;
    }
    __syncthreads();
    unsigned int* tp = tmp + (size_t)loff * TOT_E;
#pragma unroll
    for (int i = 0; i < 8; i++)
        if (cb[i] >= 0) tp[base[cb[i]] + rk[i]] = pk[i];
}

// ---------------- local bin: fine hist+scan+rowptr+dinv+scatter --------------
__global__ __launch_bounds__(256) void k_binB(const unsigned int* __restrict__ tmp,
                                              const int* __restrict__ crp,
                                              int* __restrict__ rowptr,
                                              int* __restrict__ srcs,
                                              float* __restrict__ dinv) {
    __shared__ int cnt[GSZ + 1];
    __shared__ int sc[512];
    __shared__ int cur[GSZ + 1];
    int blk = blockIdx.x;
    int l = blk >> 8, b = blk & 255;
    int t = threadIdx.x;
    int nbeg = b * GSZ;
    int ncnt = min(GSZ, N_NODES - nbeg);
    const int* crpl = crp + l * NBK;
    int ebeg = crpl[b];
    int eend = (b < NBK - 1) ? crpl[b + 1] : TOT_E;
    const unsigned int* tp = tmp + (size_t)l * TOT_E;
    for (int i = t; i < GSZ + 1; i += 256) cnt[i] = 0;
    __syncthreads();
    for (int e = ebeg + t; e < eend; e += 256)
        atomicAdd(&cnt[tp[e] >> 17], 1);
    __syncthreads();
    // inclusive Hillis-Steele over 512 slots, 2 per thread
    int t2 = t + 256;
    sc[t]  = (t  < ncnt) ? cnt[t]  : 0;
    sc[t2] = (t2 < ncnt) ? cnt[t2] : 0;
    __syncthreads();
    for (int off = 1; off < 512; off <<= 1) {
        int v0 = (t  >= off) ? sc[t  - off] : 0;
        int v1 = (t2 >= off) ? sc[t2 - off] : 0;
        __syncthreads();
        sc[t] += v0; sc[t2] += v1;
        __syncthreads();
    }
    for (int i = t; i < ncnt; i += 256) {
        int c = cnt[i];
        int gpos = ebeg + sc[i] - c;   // exclusive
        rowptr[l * N_NODES + nbeg + i] = gpos;
        cur[i] = gpos;
        if (l == 1) dinv[nbeg + i] = rsqrtf((float)c);   // c >= 1 (self-loop)
    }
    __syncthreads();
    int* so = srcs + (size_t)l * TOT_E;
    for (int e = ebeg + t; e < eend; e += 256) {
        unsigned int p = tp[e];
        int pos = atomicAdd(&cur[p >> 17], 1);
        so[pos] = (int)(p & 0x1FFFF);
    }
}

// ---------------- GAT aggregation: wave/dst, direct exp, 4-edge ILP ----------
__global__ __launch_bounds__(256) void k_gat(const float* __restrict__ h,
                                             const float* __restrict__ as_ad,
                                             const int* __restrict__ rowptr,
                                             const int* __restrict__ srcs,
                                             const float* __restrict__ b1,
                                             float* __restrict__ x1) {
    int w = (blockIdx.x * 256 + threadIdx.x) >> 6;   // wave-uniform dst node
    if (w >= N_NODES) return;
    int lane = threadIdx.x & 63;
    int hd = lane >> 4;
    float ad = as_ad[w * 8 + 4 + hd];
    int beg = rowptr[w];
    int end = (w == N_NODES - 1) ? TOT_E : rowptr[w + 1];
    float l0 = 0.f, l1 = 0.f, a0 = 0.f, a1 = 0.f;
    int j = beg;
    for (; j + 3 < end; j += 4) {
        int s0 = srcs[j], s1 = srcs[j + 1], s2 = srcs[j + 2], s3 = srcs[j + 3];
        float h0 = h[(size_t)s0 * HID + lane];
        float h1 = h[(size_t)s1 * HID + lane];
        float h2 = h[(size_t)s2 * HID + lane];
        float h3 = h[(size_t)s3 * HID + lane];
        float e0 = as_ad[s0 * 8 + hd] + ad;
        float e1 = as_ad[s1 * 8 + hd] + ad;
        float e2 = as_ad[s2 * 8 + hd] + ad;
        float e3 = as_ad[s3 * 8 + hd] + ad;
        e0 = fminf((e0 > 0.f) ? e0 : SLOPE * e0, 60.f);
        e1 = fminf((e1 > 0.f) ? e1 : SLOPE * e1, 60.f);
        e2 = fminf((e2 > 0.f) ? e2 : SLOPE * e2, 60.f);
        e3 = fminf((e3 > 0.f) ? e3 : SLOPE * e3, 60.f);
        float p0 = __expf(e0), p1 = __expf(e1), p2 = __expf(e2), p3 = __expf(e3);
        l0 += p0; l1 += p1; l0 += p2; l1 += p3;
        a0 += p0 * h0; a1 += p1 * h1; a0 += p2 * h2; a1 += p3 * h3;
    }
    for (; j < end; j++) {
        int s = srcs[j];
        float hv = h[(size_t)s * HID + lane];
        float e = as_ad[s * 8 + hd] + ad;
        e = fminf((e > 0.f) ? e : SLOPE * e, 60.f);
        float p = __expf(e);
        l0 += p; a0 += p * hv;
    }
    float l = l0 + l1, acc = a0 + a1;
    x1[(size_t)w * HID + lane] = fmaxf(acc / l + b1[lane], 0.f);
}

// ---------------- GEMM2: h2s[N,32] = (x1[N,64] @ W2[64,32]) * dinv[row] ------
__global__ __launch_bounds__(256) void k_gemm2(const float* __restrict__ x1,
                                               const float* __restrict__ W2,
                                               const float* __restrict__ dinv,
                                               float* __restrict__ h2s) {
    __shared__ float wl[HID * OUT2];   // 8 KB
    __shared__ float xl[8][HID];       // 2 KB
    int t = threadIdx.x;
    for (int i = t; i < HID * OUT2; i += 256) wl[i] = W2[i];
    int row0 = blockIdx.x * 8;
    for (int i = t; i < 8 * HID; i += 256) {
        int rr = i >> 6, kk = i & 63;
        int gr = row0 + rr;
        xl[rr][kk] = (gr < N_NODES) ? x1[(size_t)gr * HID + kk] : 0.f;
    }
    __syncthreads();
    int r = t >> 5, c = t & 31;
    float acc = 0.f;
#pragma unroll 8
    for (int k = 0; k < HID; k++) acc += xl[r][k] * wl[k * OUT2 + c];
    int gr = row0 + r;
    if (gr < N_NODES) h2s[(size_t)gr * OUT2 + c] = acc * dinv[gr];
}

// ---------------- GCN aggregation: wave/dst, 4-edge ILP ----------------------
__global__ __launch_bounds__(256) void k_gcn(const float* __restrict__ h2s,
                                             const float* __restrict__ dinv,
                                             const int* __restrict__ rowptr,
                                             const int* __restrict__ srcs,
                                             const float* __restrict__ b2,
                                             float* __restrict__ out) {
    int w = (blockIdx.x * 256 + threadIdx.x) >> 6;
    if (w >= N_NODES) return;
    int lane = threadIdx.x & 63;
    int c = lane & 31, rep = lane >> 5;
    int beg = rowptr[w];
    int end = (w == N_NODES - 1) ? TOT_E : rowptr[w + 1];
    float a0 = 0.f, a1 = 0.f;
    int j = beg + rep;
    for (; j + 2 < end; j += 4) {
        int s0 = srcs[j], s1 = srcs[j + 2];
        a0 += h2s[(size_t)s0 * OUT2 + c];
        a1 += h2s[(size_t)s1 * OUT2 + c];
    }
    if (j < end) a0 += h2s[(size_t)srcs[j] * OUT2 + c];
    float acc = a0 + a1;
    acc += __shfl_xor(acc, 32, 64);
    if (rep == 0) out[(size_t)w * OUT2 + c] = acc * dinv[w] + b2[c];
}

// ---------------- launch -----------------------------------------------------
static inline size_t align_up(size_t v, size_t a) { return (v + a - 1) & ~(a - 1); }

extern "C" void kernel_launch(void* const* d_in, const int* in_sizes, int n_in,
                              void* d_out, int out_size, void* d_ws, size_t ws_size,
                              hipStream_t stream) {
    const float* x       = (const float*)d_in[0];
    const float* W1      = (const float*)d_in[1];
    const float* att_src = (const float*)d_in[2];
    const float* att_dst = (const float*)d_in[3];
    const float* b1      = (const float*)d_in[4];
    const float* W2      = (const float*)d_in[5];
    const float* b2      = (const float*)d_in[6];
    const int*   ei1     = (const int*)d_in[7];
    const int*   ei2     = (const int*)d_in[8];
    float* out = (float*)d_out;

    char* p = (char*)d_ws;
    size_t off = 0;
    auto carve = [&](size_t bytes) { void* q = p + off; off = align_up(off + bytes, 256); return q; };
    float* h      = (float*)carve((size_t)N_NODES * HID * 4);    // 25.6 MB
    float* x1     = (float*)carve((size_t)N_NODES * HID * 4);    // 25.6 MB
    float* h2s    = (float*)carve((size_t)N_NODES * OUT2 * 4);   // 12.8 MB
    float* as_ad  = (float*)carve((size_t)N_NODES * 8 * 4);      // 3.2 MB
    float* dinv   = (float*)carve((size_t)N_NODES * 4);          // 0.4 MB
    int* rowptr   = (int*)carve((size_t)2 * N_NODES * 4);        // 0.8 MB
    int* srcs     = (int*)carve((size_t)2 * TOT_E * 4);          // 26.4 MB
    int* ccnt     = (int*)carve((size_t)2 * NBK * 4);
    int* crp      = (int*)carve((size_t)2 * NBK * 4);
    int* ccur     = (int*)carve((size_t)2 * NBK * 4);
    // tmp (26.4 MB) aliases x1+h2s (38.4 MB): dead by the time k_gat writes x1
    unsigned int* tmp = (unsigned int*)x1;
    (void)ws_size; (void)in_sizes; (void)n_in; (void)out_size;

    hipMemsetAsync(ccnt, 0, (size_t)2 * NBK * 4, stream);

    // dense pipeline
    k_gemm1<<<(N_NODES + 63) / 64, 256, 0, stream>>>(x, W1, h);
    k_scores<<<(N_NODES * HEADS + 255) / 256, 256, 0, stream>>>(h, att_src, att_dst, as_ad);

    // CSR build: coarse hist -> coarse scan -> coarse bin -> local bin
    k_chist<<<2 * NBA, 512, 0, stream>>>(ei1, ei2, ccnt);
    k_cscan<<<1, 512, 0, stream>>>(ccnt, crp, ccur);
    k_binA<<<2 * NBA, 512, 0, stream>>>(ei1, ei2, ccur, tmp);
    k_binB<<<2 * NBK, 256, 0, stream>>>(tmp, crp, rowptr, srcs, dinv);

    // GAT aggregation -> x1 (relu(+b1) fused)
    k_gat<<<N_NODES / 4, 256, 0, stream>>>(h, as_ad, rowptr, srcs, b1, x1);

    // GEMM2 -> h2s (pre-scaled by dinv[row])
    k_gemm2<<<N_NODES / 8, 256, 0, stream>>>(x1, W2, dinv, h2s);

    // GCN aggregation -> out (+b2 fused)
    k_gcn<<<N_NODES / 4, 256, 0, stream>>>(h2s, dinv, rowptr + N_NODES, srcs + TOT_E, b2, out);
}

// Round 5
// 754.166 us; speedup vs baseline: 2.2775x; 1.1098x over previous
//
#include <hip/hip_runtime.h>
#include <hip/hip_bf16.h>

#define N_NODES 100000
#define N_EDGES 3200000
#define TOT_E   (N_EDGES + N_NODES)   // edges + self loops = 3,300,000
#define HEADS   4
#define DH      16
#define IN_F    300
#define HID     64
#define OUT2    32
#define SLOPE   0.2f
#define NBK     256                   // coarse buckets per list
#define GSZ     391                   // nodes per coarse bucket (256*391 >= 100000)
#define EBLK    4096                  // edges per bin block
#define NBA     ((TOT_E + EBLK - 1) / EBLK)   // 806 blocks per list

#define G1_ROWS 128                   // rows per block (gemm1)
#define G1_KT   50                    // K-tile (300 = 6*50)
#define G1_XP   132                   // xT row stride (16B-aligned float4 reads)

// ---- GEMM1: h[N,64] = x[N,300] @ W1[300,64]; 8x4 register tile per thread ---
__global__ __launch_bounds__(256) void k_gemm1(const float* __restrict__ x,
                                               const float* __restrict__ W1,
                                               float* __restrict__ h) {
    __shared__ float xT[G1_KT][G1_XP];   // 26.4 KB, transposed x tile
    __shared__ float wl[G1_KT][HID];     // 12.8 KB
    int t = threadIdx.x;
    int row0 = blockIdx.x * G1_ROWS;
    int tc = t & 15, tr = t >> 4;        // 16 col-threads x 16 row-threads
    int c0 = tc * 4, r0 = tr * 8;
    float acc[8][4];
#pragma unroll
    for (int i = 0; i < 8; i++)
#pragma unroll
        for (int j = 0; j < 4; j++) acc[i][j] = 0.f;

    for (int kt = 0; kt < IN_F; kt += G1_KT) {
        __syncthreads();   // previous tile fully consumed
        for (int i = t; i < G1_KT * HID; i += 256)
            ((float*)wl)[i] = W1[kt * HID + i];          // wl[k][c]=W1[kt+k][c]
        for (int i = t; i < G1_ROWS * G1_KT; i += 256) {
            int r = i / G1_KT, k = i - r * G1_KT;        // coalesced global read
            int gr = row0 + r;
            xT[k][r] = (gr < N_NODES) ? x[(size_t)gr * IN_F + kt + k] : 0.f;
        }
        __syncthreads();
#pragma unroll 2
        for (int k = 0; k < G1_KT; k++) {
            float4 xa = *(const float4*)&xT[k][r0];
            float4 xb = *(const float4*)&xT[k][r0 + 4];
            float4 wv = *(const float4*)&wl[k][c0];
            acc[0][0] += xa.x * wv.x; acc[0][1] += xa.x * wv.y;
            acc[0][2] += xa.x * wv.z; acc[0][3] += xa.x * wv.w;
            acc[1][0] += xa.y * wv.x; acc[1][1] += xa.y * wv.y;
            acc[1][2] += xa.y * wv.z; acc[1][3] += xa.y * wv.w;
            acc[2][0] += xa.z * wv.x; acc[2][1] += xa.z * wv.y;
            acc[2][2] += xa.z * wv.z; acc[2][3] += xa.z * wv.w;
            acc[3][0] += xa.w * wv.x; acc[3][1] += xa.w * wv.y;
            acc[3][2] += xa.w * wv.z; acc[3][3] += xa.w * wv.w;
            acc[4][0] += xb.x * wv.x; acc[4][1] += xb.x * wv.y;
            acc[4][2] += xb.x * wv.z; acc[4][3] += xb.x * wv.w;
            acc[5][0] += xb.y * wv.x; acc[5][1] += xb.y * wv.y;
            acc[5][2] += xb.y * wv.z; acc[5][3] += xb.y * wv.w;
            acc[6][0] += xb.z * wv.x; acc[6][1] += xb.z * wv.y;
            acc[6][2] += xb.z * wv.z; acc[6][3] += xb.z * wv.w;
            acc[7][0] += xb.w * wv.x; acc[7][1] += xb.w * wv.y;
            acc[7][2] += xb.w * wv.z; acc[7][3] += xb.w * wv.w;
        }
    }
#pragma unroll
    for (int i = 0; i < 8; i++) {
        int gr = row0 + r0 + i;
        if (gr < N_NODES)
            *(float4*)&h[(size_t)gr * HID + c0] =
                make_float4(acc[i][0], acc[i][1], acc[i][2], acc[i][3]);
    }
}

// ---------------- attention scores: a_s[n,h], a_d[n,h] -----------------------
__global__ void k_scores(const float* __restrict__ h,
                         const float* __restrict__ att_src,
                         const float* __restrict__ att_dst,
                         float* __restrict__ as_ad) {
    int tid = blockIdx.x * blockDim.x + threadIdx.x;
    if (tid >= N_NODES * HEADS) return;
    int n = tid >> 2, hd = tid & 3;
    const float* hp = &h[(size_t)n * HID + hd * DH];
    float s = 0.f, d = 0.f;
#pragma unroll
    for (int k = 0; k < DH; k++) {
        float v = hp[k];
        s += v * att_src[hd * DH + k];
        d += v * att_dst[hd * DH + k];
    }
    as_ad[n * 8 + hd] = s;
    as_ad[n * 8 + 4 + hd] = d;
}

// ---------------- coarse histogram (LDS-aggregated, both lists) --------------
__global__ __launch_bounds__(512) void k_chist(const int* __restrict__ ei1,
                                               const int* __restrict__ ei2,
                                               int* __restrict__ ccnt) {
    __shared__ int hist[NBK];
    int b = blockIdx.x; const int* ei; int* cc;
    if (b < NBA) { ei = ei1; cc = ccnt; }
    else         { ei = ei2; cc = ccnt + NBK; b -= NBA; }
    int t = threadIdx.x;
    if (t < NBK) hist[t] = 0;
    __syncthreads();
    int e0 = b * EBLK;
#pragma unroll
    for (int i = 0; i < 8; i++) {
        int e = e0 + i * 512 + t;
        if (e < TOT_E) {
            int dst = (e < N_EDGES) ? ei[N_EDGES + e] : (e - N_EDGES);
            atomicAdd(&hist[(unsigned int)dst / GSZ], 1);
        }
    }
    __syncthreads();
    if (t < NBK) { int v = hist[t]; if (v) atomicAdd(&cc[t], v); }
}

// ---------------- coarse scan (1 block, 2 lists x 256) -----------------------
__global__ __launch_bounds__(512) void k_cscan(const int* __restrict__ ccnt,
                                               int* __restrict__ crp,
                                               int* __restrict__ ccur) {
    __shared__ int sc[512];
    int t = threadIdx.x;
    int idx = t & (NBK - 1);
    int own = ccnt[t];
    sc[t] = own;
    __syncthreads();
    for (int off = 1; off < NBK; off <<= 1) {
        int v = (idx >= off) ? sc[t - off] : 0;
        __syncthreads();
        sc[t] += v;
        __syncthreads();
    }
    int ex = sc[t] - own;
    crp[t] = ex; ccur[t] = ex;
}

// ---------------- coarse bin: scatter packed (dst_lo<<17 | src) --------------
__global__ __launch_bounds__(512) void k_binA(const int* __restrict__ ei1,
                                              const int* __restrict__ ei2,
                                              int* __restrict__ ccur,
                                              unsigned int* __restrict__ tmp) {
    __shared__ int hist[NBK];
    __shared__ int base[NBK];
    int b = blockIdx.x; const int* ei; int loff;
    if (b < NBA) { ei = ei1; loff = 0; }
    else         { ei = ei2; loff = 1; b -= NBA; }
    int t = threadIdx.x;
    if (t < NBK) hist[t] = 0;
    __syncthreads();
    unsigned int pk[8]; int cb[8], rk[8];
    int e0 = b * EBLK;
#pragma unroll
    for (int i = 0; i < 8; i++) {
        int e = e0 + i * 512 + t;
        cb[i] = -1;
        if (e < TOT_E) {
            int src, dst;
            if (e < N_EDGES) { src = ei[e]; dst = ei[N_EDGES + e]; }
            else             { src = e - N_EDGES; dst = src; }
            unsigned int c   = (unsigned int)dst / GSZ;
            unsigned int dlo = (unsigned int)dst - c * GSZ;
            cb[i] = (int)c;
            pk[i] = (dlo << 17) | (unsigned int)src;
            rk[i] = atomicAdd(&hist[c], 1);
        }
    }
    __syncthreads();
    if (t < NBK) {
        int v = hist[t];
        base[t] = v ? atomicAdd(&ccur[loff * NBK + t], v) : 0;
    }
    __syncthreads();
    unsigned int* tp = tmp + (size_t)loff * TOT_E;
#pragma unroll
    for (int i = 0; i < 8; i++)
        if (cb[i] >= 0) tp[base[cb[i]] + rk[i]] = pk[i];
}

// ---------------- local bin: fine hist+scan+rowptr+dinv+scatter --------------
__global__ __launch_bounds__(256) void k_binB(const unsigned int* __restrict__ tmp,
                                              const int* __restrict__ crp,
                                              int* __restrict__ rowptr,
                                              int* __restrict__ srcs,
                                              float* __restrict__ dinv) {
    __shared__ int cnt[GSZ + 1];
    __shared__ int sc[512];
    __shared__ int cur[GSZ + 1];
    int blk = blockIdx.x;
    int l = blk >> 8, b = blk & 255;
    int t = threadIdx.x;
    int nbeg = b * GSZ;
    int ncnt = min(GSZ, N_NODES - nbeg);
    const int* crpl = crp + l * NBK;
    int ebeg = crpl[b];
    int eend = (b < NBK - 1) ? crpl[b + 1] : TOT_E;
    const unsigned int* tp = tmp + (size_t)l * TOT_E;
    for (int i = t; i < GSZ + 1; i += 256) cnt[i] = 0;
    __syncthreads();
    for (int e = ebeg + t; e < eend; e += 256)
        atomicAdd(&cnt[tp[e] >> 17], 1);
    __syncthreads();
    int t2 = t + 256;
    sc[t]  = (t  < ncnt) ? cnt[t]  : 0;
    sc[t2] = (t2 < ncnt) ? cnt[t2] : 0;
    __syncthreads();
    for (int off = 1; off < 512; off <<= 1) {
        int v0 = (t  >= off) ? sc[t  - off] : 0;
        int v1 = (t2 >= off) ? sc[t2 - off] : 0;
        __syncthreads();
        sc[t] += v0; sc[t2] += v1;
        __syncthreads();
    }
    for (int i = t; i < ncnt; i += 256) {
        int c = cnt[i];
        int gpos = ebeg + sc[i] - c;   // exclusive
        rowptr[l * N_NODES + nbeg + i] = gpos;
        cur[i] = gpos;
        if (l == 1) dinv[nbeg + i] = rsqrtf((float)c);   // c >= 1 (self-loop)
    }
    __syncthreads();
    int* so = srcs + (size_t)l * TOT_E;
    for (int e = ebeg + t; e < eend; e += 256) {
        unsigned int p = tp[e];
        int pos = atomicAdd(&cur[p >> 17], 1);
        so[pos] = (int)(p & 0x1FFFF);
    }
}

// ---------------- GAT aggregation: wave/dst, direct exp, 4-edge ILP ----------
__global__ __launch_bounds__(256) void k_gat(const float* __restrict__ h,
                                             const float* __restrict__ as_ad,
                                             const int* __restrict__ rowptr,
                                             const int* __restrict__ srcs,
                                             const float* __restrict__ b1,
                                             float* __restrict__ x1) {
    int w = (blockIdx.x * 256 + threadIdx.x) >> 6;   // wave-uniform dst node
    if (w >= N_NODES) return;
    int lane = threadIdx.x & 63;
    int hd = lane >> 4;
    float ad = as_ad[w * 8 + 4 + hd];
    int beg = rowptr[w];
    int end = (w == N_NODES - 1) ? TOT_E : rowptr[w + 1];
    float l0 = 0.f, l1 = 0.f, a0 = 0.f, a1 = 0.f;
    int j = beg;
    for (; j + 3 < end; j += 4) {
        int s0 = srcs[j], s1 = srcs[j + 1], s2 = srcs[j + 2], s3 = srcs[j + 3];
        float h0 = h[(size_t)s0 * HID + lane];
        float h1 = h[(size_t)s1 * HID + lane];
        float h2 = h[(size_t)s2 * HID + lane];
        float h3 = h[(size_t)s3 * HID + lane];
        float e0 = as_ad[s0 * 8 + hd] + ad;
        float e1 = as_ad[s1 * 8 + hd] + ad;
        float e2 = as_ad[s2 * 8 + hd] + ad;
        float e3 = as_ad[s3 * 8 + hd] + ad;
        e0 = fminf((e0 > 0.f) ? e0 : SLOPE * e0, 60.f);
        e1 = fminf((e1 > 0.f) ? e1 : SLOPE * e1, 60.f);
        e2 = fminf((e2 > 0.f) ? e2 : SLOPE * e2, 60.f);
        e3 = fminf((e3 > 0.f) ? e3 : SLOPE * e3, 60.f);
        float p0 = __expf(e0), p1 = __expf(e1), p2 = __expf(e2), p3 = __expf(e3);
        l0 += p0; l1 += p1; l0 += p2; l1 += p3;
        a0 += p0 * h0; a1 += p1 * h1; a0 += p2 * h2; a1 += p3 * h3;
    }
    for (; j < end; j++) {
        int s = srcs[j];
        float hv = h[(size_t)s * HID + lane];
        float e = as_ad[s * 8 + hd] + ad;
        e = fminf((e > 0.f) ? e : SLOPE * e, 60.f);
        float p = __expf(e);
        l0 += p; a0 += p * hv;
    }
    float l = l0 + l1, acc = a0 + a1;
    x1[(size_t)w * HID + lane] = fmaxf(acc / l + b1[lane], 0.f);
}

// ---------------- GEMM2: h2s[N,32] = (x1[N,64] @ W2[64,32]) * dinv[row] ------
__global__ __launch_bounds__(256) void k_gemm2(const float* __restrict__ x1,
                                               const float* __restrict__ W2,
                                               const float* __restrict__ dinv,
                                               float* __restrict__ h2s) {
    __shared__ float wl[HID * OUT2];   // 8 KB
    __shared__ float xl[8][HID];       // 2 KB
    int t = threadIdx.x;
    for (int i = t; i < HID * OUT2; i += 256) wl[i] = W2[i];
    int row0 = blockIdx.x * 8;
    for (int i = t; i < 8 * HID; i += 256) {
        int rr = i >> 6, kk = i & 63;
        int gr = row0 + rr;
        xl[rr][kk] = (gr < N_NODES) ? x1[(size_t)gr * HID + kk] : 0.f;
    }
    __syncthreads();
    int r = t >> 5, c = t & 31;
    float acc = 0.f;
#pragma unroll 8
    for (int k = 0; k < HID; k++) acc += xl[r][k] * wl[k * OUT2 + c];
    int gr = row0 + r;
    if (gr < N_NODES) h2s[(size_t)gr * OUT2 + c] = acc * dinv[gr];
}

// ---------------- GCN aggregation: wave/dst, 4-edge ILP ----------------------
__global__ __launch_bounds__(256) void k_gcn(const float* __restrict__ h2s,
                                             const float* __restrict__ dinv,
                                             const int* __restrict__ rowptr,
                                             const int* __restrict__ srcs,
                                             const float* __restrict__ b2,
                                             float* __restrict__ out) {
    int w = (blockIdx.x * 256 + threadIdx.x) >> 6;
    if (w >= N_NODES) return;
    int lane = threadIdx.x & 63;
    int c = lane & 31, rep = lane >> 5;
    int beg = rowptr[w];
    int end = (w == N_NODES - 1) ? TOT_E : rowptr[w + 1];
    float a0 = 0.f, a1 = 0.f;
    int j = beg + rep;
    for (; j + 2 < end; j += 4) {
        int s0 = srcs[j], s1 = srcs[j + 2];
        a0 += h2s[(size_t)s0 * OUT2 + c];
        a1 += h2s[(size_t)s1 * OUT2 + c];
    }
    if (j < end) a0 += h2s[(size_t)srcs[j] * OUT2 + c];
    float acc = a0 + a1;
    acc += __shfl_xor(acc, 32, 64);
    if (rep == 0) out[(size_t)w * OUT2 + c] = acc * dinv[w] + b2[c];
}

// ---------------- launch -----------------------------------------------------
static inline size_t align_up(size_t v, size_t a) { return (v + a - 1) & ~(a - 1); }

extern "C" void kernel_launch(void* const* d_in, const int* in_sizes, int n_in,
                              void* d_out, int out_size, void* d_ws, size_t ws_size,
                              hipStream_t stream) {
    const float* x       = (const float*)d_in[0];
    const float* W1      = (const float*)d_in[1];
    const float* att_src = (const float*)d_in[2];
    const float* att_dst = (const float*)d_in[3];
    const float* b1      = (const float*)d_in[4];
    const float* W2      = (const float*)d_in[5];
    const float* b2      = (const float*)d_in[6];
    const int*   ei1     = (const int*)d_in[7];
    const int*   ei2     = (const int*)d_in[8];
    float* out = (float*)d_out;

    char* p = (char*)d_ws;
    size_t off = 0;
    auto carve = [&](size_t bytes) { void* q = p + off; off = align_up(off + bytes, 256); return q; };
    float* h      = (float*)carve((size_t)N_NODES * HID * 4);    // 25.6 MB
    float* x1     = (float*)carve((size_t)N_NODES * HID * 4);    // 25.6 MB
    float* h2s    = (float*)carve((size_t)N_NODES * OUT2 * 4);   // 12.8 MB
    float* as_ad  = (float*)carve((size_t)N_NODES * 8 * 4);      // 3.2 MB
    float* dinv   = (float*)carve((size_t)N_NODES * 4);          // 0.4 MB
    int* rowptr   = (int*)carve((size_t)2 * N_NODES * 4);        // 0.8 MB
    int* srcs     = (int*)carve((size_t)2 * TOT_E * 4);          // 26.4 MB
    int* ccnt     = (int*)carve((size_t)2 * NBK * 4);
    int* crp      = (int*)carve((size_t)2 * NBK * 4);
    int* ccur     = (int*)carve((size_t)2 * NBK * 4);
    // tmp (26.4 MB) aliases x1+h2s (38.4 MB): dead by the time k_gat writes x1
    unsigned int* tmp = (unsigned int*)x1;
    (void)ws_size; (void)in_sizes; (void)n_in; (void)out_size;

    hipMemsetAsync(ccnt, 0, (size_t)2 * NBK * 4, stream);

    // dense pipeline
    k_gemm1<<<(N_NODES + G1_ROWS - 1) / G1_ROWS, 256, 0, stream>>>(x, W1, h);
    k_scores<<<(N_NODES * HEADS + 255) / 256, 0ul ? 256 : 256, 0, stream>>>(h, att_src, att_dst, as_ad);

    // CSR build: coarse hist -> coarse scan -> coarse bin -> local bin
    k_chist<<<2 * NBA, 512, 0, stream>>>(ei1, ei2, ccnt);
    k_cscan<<<1, 512, 0, stream>>>(ccnt, crp, ccur);
    k_binA<<<2 * NBA, 512, 0, stream>>>(ei1, ei2, ccur, tmp);
    k_binB<<<2 * NBK, 256, 0, stream>>>(tmp, crp, rowptr, srcs, dinv);

    // GAT aggregation -> x1 (relu(+b1) fused)
    k_gat<<<N_NODES / 4, 256, 0, stream>>>(h, as_ad, rowptr, srcs, b1, x1);

    // GEMM2 -> h2s (pre-scaled by dinv[row])
    k_gemm2<<<N_NODES / 8, 256, 0, stream>>>(x1, W2, dinv, h2s);

    // GCN aggregation -> out (+b2 fused)
    k_gcn<<<N_NODES / 4, 256, 0, stream>>>(h2s, dinv, rowptr + N_NODES, srcs + TOT_E, b2, out);
}

// Round 6
// 704.115 us; speedup vs baseline: 2.4394x; 1.0711x over previous
//
#include <hip/hip_runtime.h>
#include <hip/hip_bf16.h>

#define N_NODES 100000
#define N_EDGES 3200000
#define TOT_E   (N_EDGES + N_NODES)   // edges + self loops = 3,300,000
#define HEADS   4
#define DH      16
#define IN_F    300
#define HID     64
#define OUT2    32
#define SLOPE   0.2f
#define NBK     256                   // coarse buckets per list
#define GSZ     391                   // nodes per coarse bucket (256*391 >= 100000)
#define EBLK    4096                  // edges per bin block
#define NBA     ((TOT_E + EBLK - 1) / EBLK)   // 806 blocks per list

#define G1_ROWS 128                   // rows per block (gemm1)
#define G1_KT   50                    // K-tile (300 = 6*50)
#define G1_XP   132                   // xT row stride (16B-aligned float4 reads)

// ---- GEMM1: h[N,64] = x[N,300] @ W1[300,64]; 8x4 register tile per thread ---
__global__ __launch_bounds__(256) void k_gemm1(const float* __restrict__ x,
                                               const float* __restrict__ W1,
                                               float* __restrict__ h) {
    __shared__ float xT[G1_KT][G1_XP];   // 26.4 KB, transposed x tile
    __shared__ float wl[G1_KT][HID];     // 12.8 KB
    int t = threadIdx.x;
    int row0 = blockIdx.x * G1_ROWS;
    int tc = t & 15, tr = t >> 4;        // 16 col-threads x 16 row-threads
    int c0 = tc * 4, r0 = tr * 8;
    float acc[8][4];
#pragma unroll
    for (int i = 0; i < 8; i++)
#pragma unroll
        for (int j = 0; j < 4; j++) acc[i][j] = 0.f;

    for (int kt = 0; kt < IN_F; kt += G1_KT) {
        __syncthreads();   // previous tile fully consumed
        for (int i = t; i < G1_KT * HID; i += 256)
            ((float*)wl)[i] = W1[kt * HID + i];          // wl[k][c]=W1[kt+k][c]
        for (int i = t; i < G1_ROWS * G1_KT; i += 256) {
            int r = i / G1_KT, k = i - r * G1_KT;        // coalesced global read
            int gr = row0 + r;
            xT[k][r] = (gr < N_NODES) ? x[(size_t)gr * IN_F + kt + k] : 0.f;
        }
        __syncthreads();
#pragma unroll 2
        for (int k = 0; k < G1_KT; k++) {
            float4 xa = *(const float4*)&xT[k][r0];
            float4 xb = *(const float4*)&xT[k][r0 + 4];
            float4 wv = *(const float4*)&wl[k][c0];
            acc[0][0] += xa.x * wv.x; acc[0][1] += xa.x * wv.y;
            acc[0][2] += xa.x * wv.z; acc[0][3] += xa.x * wv.w;
            acc[1][0] += xa.y * wv.x; acc[1][1] += xa.y * wv.y;
            acc[1][2] += xa.y * wv.z; acc[1][3] += xa.y * wv.w;
            acc[2][0] += xa.z * wv.x; acc[2][1] += xa.z * wv.y;
            acc[2][2] += xa.z * wv.z; acc[2][3] += xa.z * wv.w;
            acc[3][0] += xa.w * wv.x; acc[3][1] += xa.w * wv.y;
            acc[3][2] += xa.w * wv.z; acc[3][3] += xa.w * wv.w;
            acc[4][0] += xb.x * wv.x; acc[4][1] += xb.x * wv.y;
            acc[4][2] += xb.x * wv.z; acc[4][3] += xb.x * wv.w;
            acc[5][0] += xb.y * wv.x; acc[5][1] += xb.y * wv.y;
            acc[5][2] += xb.y * wv.z; acc[5][3] += xb.y * wv.w;
            acc[6][0] += xb.z * wv.x; acc[6][1] += xb.z * wv.y;
            acc[6][2] += xb.z * wv.z; acc[6][3] += xb.z * wv.w;
            acc[7][0] += xb.w * wv.x; acc[7][1] += xb.w * wv.y;
            acc[7][2] += xb.w * wv.z; acc[7][3] += xb.w * wv.w;
        }
    }
#pragma unroll
    for (int i = 0; i < 8; i++) {
        int gr = row0 + r0 + i;
        if (gr < N_NODES)
            *(float4*)&h[(size_t)gr * HID + c0] =
                make_float4(acc[i][0], acc[i][1], acc[i][2], acc[i][3]);
    }
}

// ---------------- attention scores: a_s[n,h], a_d[n,h] -----------------------
__global__ void k_scores(const float* __restrict__ h,
                         const float* __restrict__ att_src,
                         const float* __restrict__ att_dst,
                         float* __restrict__ as_ad) {
    int tid = blockIdx.x * blockDim.x + threadIdx.x;
    if (tid >= N_NODES * HEADS) return;
    int n = tid >> 2, hd = tid & 3;
    const float* hp = &h[(size_t)n * HID + hd * DH];
    float s = 0.f, d = 0.f;
#pragma unroll
    for (int k = 0; k < DH; k++) {
        float v = hp[k];
        s += v * att_src[hd * DH + k];
        d += v * att_dst[hd * DH + k];
    }
    as_ad[n * 8 + hd] = s;
    as_ad[n * 8 + 4 + hd] = d;
}

// ---------------- coarse histogram (LDS-aggregated, both lists) --------------
__global__ __launch_bounds__(512) void k_chist(const int* __restrict__ ei1,
                                               const int* __restrict__ ei2,
                                               int* __restrict__ ccnt) {
    __shared__ int hist[NBK];
    int b = blockIdx.x; const int* ei; int* cc;
    if (b < NBA) { ei = ei1; cc = ccnt; }
    else         { ei = ei2; cc = ccnt + NBK; b -= NBA; }
    int t = threadIdx.x;
    if (t < NBK) hist[t] = 0;
    __syncthreads();
    int e0 = b * EBLK;
#pragma unroll
    for (int i = 0; i < 8; i++) {
        int e = e0 + i * 512 + t;
        if (e < TOT_E) {
            int dst = (e < N_EDGES) ? ei[N_EDGES + e] : (e - N_EDGES);
            atomicAdd(&hist[(unsigned int)dst / GSZ], 1);
        }
    }
    __syncthreads();
    if (t < NBK) { int v = hist[t]; if (v) atomicAdd(&cc[t], v); }
}

// ---------------- coarse scan (1 block, 2 lists x 256) -----------------------
__global__ __launch_bounds__(512) void k_cscan(const int* __restrict__ ccnt,
                                               int* __restrict__ crp,
                                               int* __restrict__ ccur) {
    __shared__ int sc[512];
    int t = threadIdx.x;
    int idx = t & (NBK - 1);
    int own = ccnt[t];
    sc[t] = own;
    __syncthreads();
    for (int off = 1; off < NBK; off <<= 1) {
        int v = (idx >= off) ? sc[t - off] : 0;
        __syncthreads();
        sc[t] += v;
        __syncthreads();
    }
    int ex = sc[t] - own;
    crp[t] = ex; ccur[t] = ex;
}

// ---------------- coarse bin: scatter packed (dst_lo<<17 | src) --------------
__global__ __launch_bounds__(512) void k_binA(const int* __restrict__ ei1,
                                              const int* __restrict__ ei2,
                                              int* __restrict__ ccur,
                                              unsigned int* __restrict__ tmp) {
    __shared__ int hist[NBK];
    __shared__ int base[NBK];
    int b = blockIdx.x; const int* ei; int loff;
    if (b < NBA) { ei = ei1; loff = 0; }
    else         { ei = ei2; loff = 1; b -= NBA; }
    int t = threadIdx.x;
    if (t < NBK) hist[t] = 0;
    __syncthreads();
    unsigned int pk[8]; int cb[8], rk[8];
    int e0 = b * EBLK;
#pragma unroll
    for (int i = 0; i < 8; i++) {
        int e = e0 + i * 512 + t;
        cb[i] = -1;
        if (e < TOT_E) {
            int src, dst;
            if (e < N_EDGES) { src = ei[e]; dst = ei[N_EDGES + e]; }
            else             { src = e - N_EDGES; dst = src; }
            unsigned int c   = (unsigned int)dst / GSZ;
            unsigned int dlo = (unsigned int)dst - c * GSZ;
            cb[i] = (int)c;
            pk[i] = (dlo << 17) | (unsigned int)src;
            rk[i] = atomicAdd(&hist[c], 1);
        }
    }
    __syncthreads();
    if (t < NBK) {
        int v = hist[t];
        base[t] = v ? atomicAdd(&ccur[loff * NBK + t], v) : 0;
    }
    __syncthreads();
    unsigned int* tp = tmp + (size_t)loff * TOT_E;
#pragma unroll
    for (int i = 0; i < 8; i++)
        if (cb[i] >= 0) tp[base[cb[i]] + rk[i]] = pk[i];
}

// ---------------- local bin: fine hist+scan+rowptr+dinv+scatter --------------
__global__ __launch_bounds__(256) void k_binB(const unsigned int* __restrict__ tmp,
                                              const int* __restrict__ crp,
                                              int* __restrict__ rowptr,
                                              int* __restrict__ srcs,
                                              float* __restrict__ dinv) {
    __shared__ int cnt[GSZ + 1];
    __shared__ int sc[512];
    __shared__ int cur[GSZ + 1];
    int blk = blockIdx.x;
    int l = blk >> 8, b = blk & 255;
    int t = threadIdx.x;
    int nbeg = b * GSZ;
    int ncnt = min(GSZ, N_NODES - nbeg);
    const int* crpl = crp + l * NBK;
    int ebeg = crpl[b];
    int eend = (b < NBK - 1) ? crpl[b + 1] : TOT_E;
    const unsigned int* tp = tmp + (size_t)l * TOT_E;
    for (int i = t; i < GSZ + 1; i += 256) cnt[i] = 0;
    __syncthreads();
    for (int e = ebeg + t; e < eend; e += 256)
        atomicAdd(&cnt[tp[e] >> 17], 1);
    __syncthreads();
    int t2 = t + 256;
    sc[t]  = (t  < ncnt) ? cnt[t]  : 0;
    sc[t2] = (t2 < ncnt) ? cnt[t2] : 0;
    __syncthreads();
    for (int off = 1; off < 512; off <<= 1) {
        int v0 = (t  >= off) ? sc[t  - off] : 0;
        int v1 = (t2 >= off) ? sc[t2 - off] : 0;
        __syncthreads();
        sc[t] += v0; sc[t2] += v1;
        __syncthreads();
    }
    for (int i = t; i < ncnt; i += 256) {
        int c = cnt[i];
        int gpos = ebeg + sc[i] - c;   // exclusive
        rowptr[l * N_NODES + nbeg + i] = gpos;
        cur[i] = gpos;
        if (l == 1) dinv[nbeg + i] = rsqrtf((float)c);   // c >= 1 (self-loop)
    }
    __syncthreads();
    int* so = srcs + (size_t)l * TOT_E;
    for (int e = ebeg + t; e < eend; e += 256) {
        unsigned int p = tp[e];
        int pos = atomicAdd(&cur[p >> 17], 1);
        so[pos] = (int)(p & 0x1FFFF);
    }
}

// ---- GAT aggregation: wave/dst, lane = edge-slot(4) x col-quad(16) ----------
// One global_load_dwordx4 fetches 4 edges' h rows (1024 B / wave).
__global__ __launch_bounds__(256) void k_gat(const float* __restrict__ h,
                                             const float* __restrict__ as_ad,
                                             const int* __restrict__ rowptr,
                                             const int* __restrict__ srcs,
                                             const float* __restrict__ b1,
                                             float* __restrict__ x1) {
    int w = (blockIdx.x * 256 + threadIdx.x) >> 6;   // wave-uniform dst node
    if (w >= N_NODES) return;
    int lane = threadIdx.x & 63;
    int eidx = lane >> 4;          // edge slot 0..3
    int cl = lane & 15;            // column quad 0..15
    int hd = cl >> 2;              // head of my columns
    int c0 = cl * 4;
    float ad = as_ad[w * 8 + 4 + hd];
    int beg = rowptr[w];
    int end = (w == N_NODES - 1) ? TOT_E : rowptr[w + 1];
    float l = 0.f;
    float ax = 0.f, ay = 0.f, az = 0.f, aw = 0.f;
#pragma unroll 2
    for (int j = beg; j < end; j += 4) {
        int je = j + eidx;
        int s = srcs[min(je, end - 1)];
        float4 h4 = *(const float4*)&h[(size_t)s * HID + c0];
        float e = as_ad[s * 8 + hd] + ad;
        e = fminf((e > 0.f) ? e : SLOPE * e, 60.f);
        float p = (je < end) ? __expf(e) : 0.f;
        l += p;
        ax += p * h4.x; ay += p * h4.y; az += p * h4.z; aw += p * h4.w;
    }
    // reduce across the 4 edge slots (lane bits 4,5)
    l  += __shfl_xor(l, 16, 64);  l  += __shfl_xor(l, 32, 64);
    ax += __shfl_xor(ax, 16, 64); ax += __shfl_xor(ax, 32, 64);
    ay += __shfl_xor(ay, 16, 64); ay += __shfl_xor(ay, 32, 64);
    az += __shfl_xor(az, 16, 64); az += __shfl_xor(az, 32, 64);
    aw += __shfl_xor(aw, 16, 64); aw += __shfl_xor(aw, 32, 64);
    if (eidx == 0) {
        float4 bv = *(const float4*)&b1[c0];
        float rl = 1.f / l;
        float4 o = make_float4(fmaxf(ax * rl + bv.x, 0.f),
                               fmaxf(ay * rl + bv.y, 0.f),
                               fmaxf(az * rl + bv.z, 0.f),
                               fmaxf(aw * rl + bv.w, 0.f));
        *(float4*)&x1[(size_t)w * HID + c0] = o;
    }
}

// ---------------- GEMM2: h2s[N,32] = (x1[N,64] @ W2[64,32]) * dinv[row] ------
__global__ __launch_bounds__(256) void k_gemm2(const float* __restrict__ x1,
                                               const float* __restrict__ W2,
                                               const float* __restrict__ dinv,
                                               float* __restrict__ h2s) {
    __shared__ float wl[HID * OUT2];   // 8 KB
    __shared__ float xl[8][HID];       // 2 KB
    int t = threadIdx.x;
    for (int i = t; i < HID * OUT2; i += 256) wl[i] = W2[i];
    int row0 = blockIdx.x * 8;
    for (int i = t; i < 8 * HID; i += 256) {
        int rr = i >> 6, kk = i & 63;
        int gr = row0 + rr;
        xl[rr][kk] = (gr < N_NODES) ? x1[(size_t)gr * HID + kk] : 0.f;
    }
    __syncthreads();
    int r = t >> 5, c = t & 31;
    float acc = 0.f;
#pragma unroll 8
    for (int k = 0; k < HID; k++) acc += xl[r][k] * wl[k * OUT2 + c];
    int gr = row0 + r;
    if (gr < N_NODES) h2s[(size_t)gr * OUT2 + c] = acc * dinv[gr];
}

// ---- GCN aggregation: wave/dst, lane = edge-slot(8) x col-quad(8) -----------
// One global_load_dwordx4 fetches 8 edges' h2s rows (1024 B / wave).
__global__ __launch_bounds__(256) void k_gcn(const float* __restrict__ h2s,
                                             const float* __restrict__ dinv,
                                             const int* __restrict__ rowptr,
                                             const int* __restrict__ srcs,
                                             const float* __restrict__ b2,
                                             float* __restrict__ out) {
    int w = (blockIdx.x * 256 + threadIdx.x) >> 6;
    if (w >= N_NODES) return;
    int lane = threadIdx.x & 63;
    int eidx = lane >> 3;          // edge slot 0..7
    int cq = lane & 7;             // column quad 0..7
    int c0 = cq * 4;
    int beg = rowptr[w];
    int end = (w == N_NODES - 1) ? TOT_E : rowptr[w + 1];
    float ax = 0.f, ay = 0.f, az = 0.f, aw = 0.f;
#pragma unroll 2
    for (int j = beg; j < end; j += 8) {
        int je = j + eidx;
        int s = srcs[min(je, end - 1)];
        float4 h4 = *(const float4*)&h2s[(size_t)s * OUT2 + c0];
        if (je < end) { ax += h4.x; ay += h4.y; az += h4.z; aw += h4.w; }
    }
    // reduce across the 8 edge slots (lane bits 3,4,5)
    ax += __shfl_xor(ax, 8, 64); ax += __shfl_xor(ax, 16, 64); ax += __shfl_xor(ax, 32, 64);
    ay += __shfl_xor(ay, 8, 64); ay += __shfl_xor(ay, 16, 64); ay += __shfl_xor(ay, 32, 64);
    az += __shfl_xor(az, 8, 64); az += __shfl_xor(az, 16, 64); az += __shfl_xor(az, 32, 64);
    aw += __shfl_xor(aw, 8, 64); aw += __shfl_xor(aw, 16, 64); aw += __shfl_xor(aw, 32, 64);
    if (eidx == 0) {
        float dv = dinv[w];
        float4 bv = *(const float4*)&b2[c0];
        float4 o = make_float4(ax * dv + bv.x, ay * dv + bv.y,
                               az * dv + bv.z, aw * dv + bv.w);
        *(float4*)&out[(size_t)w * OUT2 + c0] = o;
    }
}

// ---------------- launch -----------------------------------------------------
static inline size_t align_up(size_t v, size_t a) { return (v + a - 1) & ~(a - 1); }

extern "C" void kernel_launch(void* const* d_in, const int* in_sizes, int n_in,
                              void* d_out, int out_size, void* d_ws, size_t ws_size,
                              hipStream_t stream) {
    const float* x       = (const float*)d_in[0];
    const float* W1      = (const float*)d_in[1];
    const float* att_src = (const float*)d_in[2];
    const float* att_dst = (const float*)d_in[3];
    const float* b1      = (const float*)d_in[4];
    const float* W2      = (const float*)d_in[5];
    const float* b2      = (const float*)d_in[6];
    const int*   ei1     = (const int*)d_in[7];
    const int*   ei2     = (const int*)d_in[8];
    float* out = (float*)d_out;

    char* p = (char*)d_ws;
    size_t off = 0;
    auto carve = [&](size_t bytes) { void* q = p + off; off = align_up(off + bytes, 256); return q; };
    float* h      = (float*)carve((size_t)N_NODES * HID * 4);    // 25.6 MB
    float* x1     = (float*)carve((size_t)N_NODES * HID * 4);    // 25.6 MB
    float* h2s    = (float*)carve((size_t)N_NODES * OUT2 * 4);   // 12.8 MB
    float* as_ad  = (float*)carve((size_t)N_NODES * 8 * 4);      // 3.2 MB
    float* dinv   = (float*)carve((size_t)N_NODES * 4);          // 0.4 MB
    int* rowptr   = (int*)carve((size_t)2 * N_NODES * 4);        // 0.8 MB
    int* srcs     = (int*)carve((size_t)2 * TOT_E * 4);          // 26.4 MB
    int* ccnt     = (int*)carve((size_t)2 * NBK * 4);
    int* crp      = (int*)carve((size_t)2 * NBK * 4);
    int* ccur     = (int*)carve((size_t)2 * NBK * 4);
    // tmp (26.4 MB) aliases x1+h2s (38.4 MB): dead by the time k_gat writes x1
    unsigned int* tmp = (unsigned int*)x1;
    (void)ws_size; (void)in_sizes; (void)n_in; (void)out_size;

    hipMemsetAsync(ccnt, 0, (size_t)2 * NBK * 4, stream);

    // dense pipeline
    k_gemm1<<<(N_NODES + G1_ROWS - 1) / G1_ROWS, 256, 0, stream>>>(x, W1, h);
    k_scores<<<(N_NODES * HEADS + 255) / 256, 256, 0, stream>>>(h, att_src, att_dst, as_ad);

    // CSR build: coarse hist -> coarse scan -> coarse bin -> local bin
    k_chist<<<2 * NBA, 512, 0, stream>>>(ei1, ei2, ccnt);
    k_cscan<<<1, 512, 0, stream>>>(ccnt, crp, ccur);
    k_binA<<<2 * NBA, 512, 0, stream>>>(ei1, ei2, ccur, tmp);
    k_binB<<<2 * NBK, 256, 0, stream>>>(tmp, crp, rowptr, srcs, dinv);

    // GAT aggregation -> x1 (relu(+b1) fused)
    k_gat<<<N_NODES / 4, 256, 0, stream>>>(h, as_ad, rowptr, srcs, b1, x1);

    // GEMM2 -> h2s (pre-scaled by dinv[row])
    k_gemm2<<<N_NODES / 8, 256, 0, stream>>>(x1, W2, dinv, h2s);

    // GCN aggregation -> out (+b2 fused)
    k_gcn<<<N_NODES / 4, 256, 0, stream>>>(h2s, dinv, rowptr + N_NODES, srcs + TOT_E, b2, out);
}